// Round 5
// baseline (222.265 us; speedup 1.0000x reference)
//
#include <hip/hip_runtime.h>
#include <stdint.h>

// proj = einsum('bit,ih->tbh', x, W); scan: h=relu(p+0.8h(1-y)); y=thr(h+b,1).
// B=64, K=512, T=512, H=1024 fp32. Output: final y (64x1024).
//
// R10: counted-vmcnt 3-ring. Re-derived budget: f16 16x16x32 MFMA = ~19.4
// cyc/instr/SIMD -> floor 3878 cyc/kt (256x256 tile); observed 6750. All
// prior rounds drained vmcnt(0) every kt (R9's phases kept the drain) —
// m218: 8-phase-with-drain0 ~= 1-phase; counted-vmcnt is the whole gain.
// This round: HB=128 (R8's proven bit-exact geometry: 8 waves x 64x64,
// 4x4 acc), staging ring of THREE 48KB buffers (144KB LDS). 6 loads per
// thread per stage. Per kt: {s_waitcnt vmcnt(6) lgkmcnt(0); s_barrier;
// sched_barrier; stage(kt+2 -> ring[(kt+2)%3]); 16 ds_read frags;
// setprio(1) 48 MFMA setprio(0)} — the DMA queue never empties; loads
// get ~2 kt (~4000cyc) to land. lgkmcnt(0) in the same wait makes the
// ring recycle race-free (readers drained pre-barrier, overwriting DMA
// issued post-barrier). Last kt waits vmcnt(0). Epilogue P[64][128] on
// RING[2] (dead at boundary); next-tile prologue staged into RING[0/1]
// under the epilogue (its __syncthreads vmcnt-drain is once/t-tile,
// harmless). Accumulation order identical to R8 -> absmax 0.03125.

#define NB 64
#define NK 512
#define NT 512
#define NH 1024

#define TB 256     // t per block tile
#define HB 128     // h per block tile
#define KK 32      // k per step
#define NKT (NK / KK)   // 16

typedef _Float16 h8_t __attribute__((ext_vector_type(8)));
typedef float    f4_t __attribute__((ext_vector_type(4)));

#define AS1 __attribute__((address_space(1)))
#define AS3 __attribute__((address_space(3)))

__device__ __forceinline__ void async_copy16(const _Float16* g, _Float16* l) {
    __builtin_amdgcn_global_load_lds((const AS1 uint32_t*)g, (AS3 uint32_t*)l, 16, 0, 0);
}

// ---- pre-pass (unchanged from R6): fp32 [rows][C] -> fp16 hi/lo in
// fragment order, coalesced float4 reads, dense h8 stores.
__global__ __launch_bounds__(256) void split_tc(
    const float* __restrict__ X, const float* __restrict__ Wm,
    _Float16* __restrict__ xhi, _Float16* __restrict__ xlo,
    _Float16* __restrict__ whi, _Float16* __restrict__ wlo)
{
    const int tid = threadIdx.x;
    const int cq  = tid & 15;     // col quad 0..15
    const int u   = tid >> 4;     // row octet 0..15

    const float* src;
    _Float16 *dhi, *dlo;
    int C, col0, row0, ktbase;

    if (blockIdx.z < 32) {
        const int idx = blockIdx.y * 16 + blockIdx.x;   // 0..63
        const int b   = blockIdx.z * 2 + (idx >> 5);    // 0..63
        const int i5  = idx & 31;
        const int bx  = i5 & 7;                          // col tile 0..7
        const int by  = i5 >> 3;                         // row tile 0..3
        C      = NT;                                     // 512
        src    = X + (size_t)b * NK * NT;
        dhi    = xhi;  dlo = xlo;
        col0   = bx * 64;
        row0   = by * 128;
        ktbase = b * 16 + by * 4;
    } else {
        const int bx = blockIdx.x;                       // 0..15
        const int by = blockIdx.y;                       // 0..3
        C      = NH;                                     // 1024
        src    = Wm;
        dhi    = whi;  dlo = wlo;
        col0   = bx * 64;
        row0   = by * 128;
        ktbase = by * 4;
    }

    const float* s = src + (size_t)(row0 + u * 8) * C + col0 + cq * 4;

    f4_t v[8];
    #pragma unroll
    for (int j = 0; j < 8; ++j)
        v[j] = *(const f4_t*)(s + (size_t)j * C);

    const int kt = ktbase + (u >> 2);
    const int ck = u & 3;

    #pragma unroll
    for (int i = 0; i < 4; ++i) {
        h8_t hi, lo;
        #pragma unroll
        for (int j = 0; j < 8; ++j) {
            float f = v[j][i] * 64.0f;       // 2^6 pre-scale
            _Float16 hh = (_Float16)f;
            hi[j] = hh;
            lo[j] = (_Float16)(f - (float)hh);
        }
        const int col = col0 + cq * 4 + i;
        const int ckp = ck ^ ((col >> 1) & 3);
        const size_t off = ((size_t)kt * C + col) * 32 + (size_t)ckp * 8;
        *(h8_t*)(dhi + off) = hi;
        *(h8_t*)(dlo + off) = lo;
    }
}

// ---------------- main fused kernel (R10: counted-vmcnt 3-ring) ----------------
// Per-buffer layout (halfs): Ahi[0,8192) Alo[8192,16384) Bhi[16384,20480) Blo[20480,24576)
#define OF_ALO 8192
#define OF_BHI 16384
#define OF_BLO 20480

__global__ __launch_bounds__(512, 2) void fused_main(
    const _Float16* __restrict__ xhi, const _Float16* __restrict__ xlo,
    const _Float16* __restrict__ whi, const _Float16* __restrict__ wlo,
    const float* __restrict__ bias, float* __restrict__ out)
{
    __shared__ __align__(16) _Float16 RING[3][24576];   // 3 x 48 KB = 144 KB
    float* Pf = (float*)&RING[2][0];                    // epilogue P[64][128]

    const int tid  = threadIdx.x;
    const int lane = tid & 63;
    const int wid  = tid >> 6;     // 0..7
    const int l15  = lane & 15;
    const int lq   = lane >> 4;    // 0..3
    const int wm   = wid >> 1;     // t quarter 0..3 (64 rows each)
    const int wn   = wid & 1;      // h half 0..1 (64 cols each)

    const int b  = blockIdx.x;
    const int h0 = blockIdx.y * HB;

    // fragment LDS offsets (halfs); chunk swizzle matches pre-pass
    const int sw   = (l15 >> 1) & 3;
    const int aoff = ((wm * 64 + l15) * 4 + (lq ^ sw)) * 8;   // + mi*512
    const int boff = ((wn * 64 + l15) * 4 + (lq ^ sw)) * 8;   // + ni*512

    float hs = 0.0f, ys = 0.0f, bv = 0.0f;
    if (tid < HB) bv = bias[h0 + tid];

    const float INV_SCALE = 1.0f / 4096.0f;   // undo 2^6 x 2^6 operand scales

    // stage tile (tt, kt) into ring buffer: exactly 6 loads per thread,
    // issue order Ahi,Alo,Ahi,Alo,Bhi,Blo. LDS dest = uniform base + lane*16.
    auto stage = [&](int tt, int kt, _Float16* buf) {
        const _Float16* ga_hi = xhi + ((size_t)(b * 16 + kt) * NT + tt) * KK;
        const _Float16* ga_lo = xlo + ((size_t)(b * 16 + kt) * NT + tt) * KK;
        const _Float16* gb_hi = whi + ((size_t)kt * NH + h0) * KK;
        const _Float16* gb_lo = wlo + ((size_t)kt * NH + h0) * KK;
        #pragma unroll
        for (int c = 0; c < 2; ++c) {
            const int ch = tid + c * 512;
            async_copy16(ga_hi + ch * 8, buf + ch * 8);
            async_copy16(ga_lo + ch * 8, buf + OF_ALO + ch * 8);
        }
        async_copy16(gb_hi + tid * 8, buf + OF_BHI + tid * 8);
        async_copy16(gb_lo + tid * 8, buf + OF_BLO + tid * 8);
    };

    f4_t acc[4][4];

    // prologue: fill 2 ring slots for the first t-tile
    stage(0, 0, RING[0]);
    stage(0, 1, RING[1]);

    for (int tt0 = 0; tt0 < NT; tt0 += TB) {
        #pragma unroll
        for (int mi = 0; mi < 4; ++mi)
            #pragma unroll
            for (int ni = 0; ni < 4; ++ni) {
                f4_t z = {0.f, 0.f, 0.f, 0.f};
                acc[mi][ni] = z;
            }

        #pragma unroll
        for (int kt = 0; kt < NKT; ++kt) {
            // counted wait: kt's 6 loads are older than kt+1's 6 -> vmcnt(6).
            // lgkmcnt(0): my frag-reads of the to-be-recycled buffer retired
            // before the barrier; the overwriting DMA is issued after it.
            if (kt == NKT - 1)
                asm volatile("s_waitcnt vmcnt(0) lgkmcnt(0)" ::: "memory");
            else
                asm volatile("s_waitcnt vmcnt(6) lgkmcnt(0)" ::: "memory");
            __builtin_amdgcn_s_barrier();
            __builtin_amdgcn_sched_barrier(0);

            if (kt + 2 < NKT) stage(tt0, kt + 2, RING[(kt + 2) % 3]);

            const _Float16* buf = &RING[kt % 3][0];
            h8_t bh[4], bl[4];
            #pragma unroll
            for (int ni = 0; ni < 4; ++ni) {
                bh[ni] = *(const h8_t*)(buf + OF_BHI + boff + ni * 512);
                bl[ni] = *(const h8_t*)(buf + OF_BLO + boff + ni * 512);
            }
            __builtin_amdgcn_s_setprio(1);
            #pragma unroll
            for (int mi = 0; mi < 4; ++mi) {
                h8_t ah = *(const h8_t*)(buf + aoff + mi * 512);
                h8_t al = *(const h8_t*)(buf + OF_ALO + aoff + mi * 512);
                #pragma unroll
                for (int ni = 0; ni < 4; ++ni) {
                    acc[mi][ni] = __builtin_amdgcn_mfma_f32_16x16x32_f16(ah, bh[ni], acc[mi][ni], 0, 0, 0);
                    acc[mi][ni] = __builtin_amdgcn_mfma_f32_16x16x32_f16(ah, bl[ni], acc[mi][ni], 0, 0, 0);
                    acc[mi][ni] = __builtin_amdgcn_mfma_f32_16x16x32_f16(al, bh[ni], acc[mi][ni], 0, 0, 0);
                }
            }
            __builtin_amdgcn_s_setprio(0);
        }

        // t-tile boundary: vmem already drained (last kt waited vmcnt(0),
        // issued nothing). Drain frag-reads + barrier so every ring buffer
        // is dead, then pre-issue next tile's first two stages (overlap
        // the epilogue; they target RING[0/1], epilogue P is RING[2]).
        asm volatile("s_waitcnt lgkmcnt(0)" ::: "memory");
        __builtin_amdgcn_s_barrier();
        __builtin_amdgcn_sched_barrier(0);
        if (tt0 + TB < NT) {
            stage(tt0 + TB, 0, RING[0]);
            stage(tt0 + TB, 1, RING[1]);
        }

        // epilogue: 4 t-subtiles x 64 rows; P[64][128] fp32 on RING[2].
        // Swizzle col' = col ^ (((row>>2)&3)<<4); (row>>2)&3 == lq on write.
        #pragma unroll 1
        for (int sub = 0; sub < 4; ++sub) {
            if (wm == sub) {
                #pragma unroll
                for (int mi = 0; mi < 4; ++mi)
                    #pragma unroll
                    for (int ni = 0; ni < 4; ++ni)
                        #pragma unroll
                        for (int r = 0; r < 4; ++r) {
                            const int row = mi * 16 + lq * 4 + r;
                            const int col = (wn * 64 + ni * 16 + l15) ^ (lq << 4);
                            Pf[row * 128 + col] = acc[mi][ni][r] * INV_SCALE;
                        }
            }
            __syncthreads();
            if (tid < HB) {
                const int cc = tid;   // h within block tile, 0..127
                #pragma unroll 8
                for (int m = 0; m < 64; ++m) {
                    float p = Pf[m * 128 + (cc ^ (((m >> 2) & 3) << 4))];
                    float pre = p + 0.8f * hs * (1.0f - ys);
                    hs = pre > 0.0f ? pre : 0.0f;
                    float z = hs + bv;
                    ys = (z > 1.0f) ? z : 0.0f;
                }
            }
            __syncthreads();   // scan done before next sub / next k-loop
        }
    }

    if (tid < HB)
        out[(size_t)b * NH + h0 + tid] = ys;
}

extern "C" void kernel_launch(void* const* d_in, const int* in_sizes, int n_in,
                              void* d_out, int out_size, void* d_ws, size_t ws_size,
                              hipStream_t stream) {
    const float* x    = (const float*)d_in[0];  // [64][512][512]
    const float* W    = (const float*)d_in[1];  // [512][1024]
    const float* bias = (const float*)d_in[2];  // [1024]
    float* out = (float*)d_out;

    _Float16* xhi = (_Float16*)d_ws;
    _Float16* xlo = xhi + (size_t)NB * NK * NT;
    _Float16* whi = xlo + (size_t)NB * NK * NT;
    _Float16* wlo = whi + (size_t)NK * NH;

    split_tc<<<dim3(16, 4, 33), 256, 0, stream>>>(x, W, xhi, xlo, whi, wlo);
    fused_main<<<dim3(NB, NH / HB), 512, 0, stream>>>(xhi, xlo, whi, wlo, bias, out);
}

// Round 6
// 203.197 us; speedup vs baseline: 1.0938x; 1.0938x over previous
//
#include <hip/hip_runtime.h>
#include <stdint.h>

// proj = einsum('bit,ih->tbh', x, W); scan: h=relu(p+0.8h(1-y)); y=thr(h+b,1).
// B=64, K=512, T=512, H=1024 fp32. Output: final y (64x1024).
//
// R11: kill the x-prepass; split fp32->fp16 hi/lo inside fused_main.
// R5-R10 evidence: six k-loop schedules all land 95-104us (MfmaUtil 43-48%)
// while the residual (total - fused) sits at a constant 91-100us — as big
// as fused itself. The prepass exists only to transpose+split x (120 of
// its 132 MB) and forces a 132 MB workspace. This round: fused stages the
// raw fp32 x-tile [32k][257-pad t] via global_load_lds (x rows are
// t-contiguous; one 1KB row per wave keeps the padded dest wave-uniform),
// reads 8 k-values per lane as ds_read_b32 (pad 257 -> bank=(k+t)%32 ->
// exactly 2-way = free), and does the bit-identical split in VALU:
// f=v*64; hh=(h)f; hl=(h)(f-(float)hh). Same MFMA order -> absmax 0.03125.
// W keeps its tiny prepass (4 MB, reused by all 64 batches). Removes
// 120 MB of prepass HBM round-trip + the 2112-block dispatch + 128 MB of
// workspace. k-loop = R7's proven dbuf shape (best measured, 95us);
// R10's ring/sched_barrier experiment reverted.

#define NB 64
#define NK 512
#define NT 512
#define NH 1024

#define TB 256     // t per block tile
#define HB 256     // h per block tile
#define KK 32      // k per step
#define NKT (NK / KK)   // 16
#define AP 257     // padded fp32 row stride (floats) for staged A

typedef _Float16 h8_t __attribute__((ext_vector_type(8)));
typedef float    f4_t __attribute__((ext_vector_type(4)));

#define AS1 __attribute__((address_space(1)))
#define AS3 __attribute__((address_space(3)))

__device__ __forceinline__ void async_copy16(const void* g, void* l) {
    __builtin_amdgcn_global_load_lds((const AS1 uint32_t*)g, (AS3 uint32_t*)l, 16, 0, 0);
}

// full drain + barrier: one per k-iteration (R7 proven shape)
__device__ __forceinline__ void wait_all_barrier() {
    __builtin_amdgcn_s_waitcnt(0);   // vmcnt(0) expcnt(0) lgkmcnt(0)
    __syncthreads();
}

// ---- W-only pre-pass: fp32 [512][1024] -> fp16 hi/lo in fragment order
// (identical math/layout to prior rounds' split, x-branch removed).
__global__ __launch_bounds__(256) void split_w(
    const float* __restrict__ Wm, _Float16* __restrict__ whi,
    _Float16* __restrict__ wlo)
{
    const int tid = threadIdx.x;
    const int cq  = tid & 15;     // col quad 0..15
    const int u   = tid >> 4;     // row octet 0..15

    const int bx = blockIdx.x;    // 0..15
    const int by = blockIdx.y;    // 0..3
    const int C  = NH;
    const int col0 = bx * 64;
    const int row0 = by * 128;
    const int ktbase = by * 4;

    const float* s = Wm + (size_t)(row0 + u * 8) * C + col0 + cq * 4;

    f4_t v[8];
    #pragma unroll
    for (int j = 0; j < 8; ++j)
        v[j] = *(const f4_t*)(s + (size_t)j * C);

    const int kt = ktbase + (u >> 2);
    const int ck = u & 3;

    #pragma unroll
    for (int i = 0; i < 4; ++i) {
        h8_t hi, lo;
        #pragma unroll
        for (int j = 0; j < 8; ++j) {
            float f = v[j][i] * 64.0f;       // 2^6 pre-scale
            _Float16 hh = (_Float16)f;
            hi[j] = hh;
            lo[j] = (_Float16)(f - (float)hh);
        }
        const int col = col0 + cq * 4 + i;
        const int ckp = ck ^ ((col >> 1) & 3);
        const size_t off = ((size_t)kt * C + col) * 32 + (size_t)ckp * 8;
        *(h8_t*)(whi + off) = hi;
        *(h8_t*)(wlo + off) = lo;
    }
}

// ---------------- main fused kernel (R11: in-kernel x split) ----------------
__global__ __launch_bounds__(512, 2) void fused_main(
    const float* __restrict__ X,
    const _Float16* __restrict__ whi, const _Float16* __restrict__ wlo,
    const float* __restrict__ bias, float* __restrict__ out)
{
    // A staged raw fp32, k-major with pad: [buf][k=32][t=256 (+1 pad)]
    __shared__ __align__(16) float SA[2][KK * AP];        // 65,792 B
    // B staged fp16 hi/lo (prepass fragment order): [buf][hi/lo][HB*KK]
    __shared__ __align__(16) _Float16 SB[2][2][HB * KK];  // 65,536 B
    // Epilogue P[64][256] fp32 (65,536 B) aliases SA (dead between k-loops)
    float* Pf = (float*)&SA[0][0];

    const int tid  = threadIdx.x;
    const int lane = tid & 63;
    const int wid  = tid >> 6;     // 0..7
    const int l15  = lane & 15;
    const int lq   = lane >> 4;    // 0..3
    const int wm   = wid >> 1;     // t quarter 0..3
    const int wn   = wid & 1;      // h half 0..1

    const int b  = blockIdx.x;
    const int h0 = blockIdx.y * HB;

    // B fragment LDS offset (halfs); chunk swizzle matches prepass
    const int sw   = (l15 >> 1) & 3;
    const int boff = ((wn * 128 + l15) * 4 + (lq ^ sw)) * 8;  // + ni*512

    float hs = 0.0f, ys = 0.0f, bv = 0.0f;
    if (tid < HB) bv = bias[h0 + tid];

    const float INV_SCALE = 1.0f / 4096.0f;   // undo 2^6 x 2^6 operand scales

    // stage A tile (tt,kt): 32 rows x 1KB fp32, one row per wave per copy.
    // Padded dest stays legal: within a copy the wave's LDS base is uniform
    // (row*AP) and HW adds lane*16.
    auto stage_A = [&](int tt, int kt, int buf) {
        #pragma unroll
        for (int c = 0; c < 4; ++c) {
            const int row = wid * 4 + c;   // wave-uniform
            const float* g = X + ((size_t)(b * NK + kt * KK + row)) * NT + tt + lane * 4;
            async_copy16(g, &SA[buf][row * AP + lane * 4]);
        }
    };
    auto stage_B = [&](int kt, int buf) {
        const _Float16* gb_hi = whi + ((size_t)kt * NH + h0) * KK;
        const _Float16* gb_lo = wlo + ((size_t)kt * NH + h0) * KK;
        #pragma unroll
        for (int c = 0; c < 2; ++c) {
            const int ch = tid + c * 512;
            async_copy16(gb_hi + ch * 8, &SB[buf][0][ch * 8]);
            async_copy16(gb_lo + ch * 8, &SB[buf][1][ch * 8]);
        }
    };

    f4_t acc[4][8];

    stage_A(0, 0, 0);   // prologue for first t-tile
    stage_B(0, 0);

    for (int tt0 = 0; tt0 < NT; tt0 += TB) {
        #pragma unroll
        for (int mi = 0; mi < 4; ++mi)
            #pragma unroll
            for (int ni = 0; ni < 8; ++ni) {
                f4_t z = {0.f, 0.f, 0.f, 0.f};
                acc[mi][ni] = z;
            }

        wait_all_barrier();   // prefetched buf0 landed block-wide

        for (int kt = 0; kt < NKT; ++kt) {
            const int cur = kt & 1;
            // issue next tile's DMA into the other buffer; flies under MFMA
            if (kt + 1 < NKT) { stage_A(tt0, kt + 1, cur ^ 1); stage_B(kt + 1, cur ^ 1); }

            h8_t bh[8], bl[8];
            #pragma unroll
            for (int ni = 0; ni < 8; ++ni) {
                bh[ni] = *(const h8_t*)(&SB[cur][0][boff + ni * 512]);
                bl[ni] = *(const h8_t*)(&SB[cur][1][boff + ni * 512]);
            }
            __builtin_amdgcn_s_setprio(1);
            #pragma unroll
            for (int mi = 0; mi < 4; ++mi) {
                // A frags: 8 scalar fp32 reads (2-way banks, free), split in VALU.
                // Bit-identical to prepass: f = x*64; hh = (h)f; hl = (h)(f - (float)hh)
                const int trow = wm * 64 + mi * 16 + l15;
                float av[8];
                #pragma unroll
                for (int j = 0; j < 8; ++j)
                    av[j] = SA[cur][(lq * 8 + j) * AP + trow];
                h8_t ah, al;
                #pragma unroll
                for (int j = 0; j < 8; ++j) {
                    float f = av[j] * 64.0f;
                    _Float16 hh = (_Float16)f;
                    ah[j] = hh;
                    al[j] = (_Float16)(f - (float)hh);
                }
                #pragma unroll
                for (int ni = 0; ni < 8; ++ni) {
                    acc[mi][ni] = __builtin_amdgcn_mfma_f32_16x16x32_f16(ah, bh[ni], acc[mi][ni], 0, 0, 0);
                    acc[mi][ni] = __builtin_amdgcn_mfma_f32_16x16x32_f16(ah, bl[ni], acc[mi][ni], 0, 0, 0);
                    acc[mi][ni] = __builtin_amdgcn_mfma_f32_16x16x32_f16(al, bh[ni], acc[mi][ni], 0, 0, 0);
                }
            }
            __builtin_amdgcn_s_setprio(0);

            wait_all_barrier();   // next-buf DMA landed; all frag reads retired
        }

        // epilogue: 4 t-subtiles x 64 rows; P[64][256] fp32 aliased on SA.
        // Swizzle: col' = col ^ (((row>>2)&1)<<4); writer key (lq&1) == reader
        // key ((m>>2)&1) since row = mi*16 + lq*4 + r. 2-way banks both sides.
        #pragma unroll 1
        for (int sub = 0; sub < 4; ++sub) {
            if (wm == sub) {
                #pragma unroll
                for (int mi = 0; mi < 4; ++mi)
                    #pragma unroll
                    for (int ni = 0; ni < 8; ++ni)
                        #pragma unroll
                        for (int r = 0; r < 4; ++r) {
                            const int row = mi * 16 + lq * 4 + r;
                            const int col = (wn * 128 + ni * 16 + l15) ^ ((lq & 1) << 4);
                            Pf[row * 256 + col] = acc[mi][ni][r] * INV_SCALE;
                        }
            }
            __syncthreads();
            if (tid < HB) {
                const int cc = tid;   // h within block tile, 0..255
                #pragma unroll 8
                for (int m = 0; m < 64; ++m) {
                    float p = Pf[m * 256 + (cc ^ (((m >> 2) & 1) << 4))];
                    float pre = p + 0.8f * hs * (1.0f - ys);
                    hs = pre > 0.0f ? pre : 0.0f;
                    float z = hs + bv;
                    ys = (z > 1.0f) ? z : 0.0f;
                }
            }
            __syncthreads();   // scan done before next sub overwrites P
        }

        // pre-issue next t-tile's first stages (P is dead; loop-top barrier
        // covers landing)
        if (tt0 + TB < NT) { stage_A(tt0 + TB, 0, 0); stage_B(0, 0); }
    }

    if (tid < HB)
        out[(size_t)b * NH + h0 + tid] = ys;
}

extern "C" void kernel_launch(void* const* d_in, const int* in_sizes, int n_in,
                              void* d_out, int out_size, void* d_ws, size_t ws_size,
                              hipStream_t stream) {
    const float* x    = (const float*)d_in[0];  // [64][512][512]
    const float* W    = (const float*)d_in[1];  // [512][1024]
    const float* bias = (const float*)d_in[2];  // [1024]
    float* out = (float*)d_out;

    _Float16* whi = (_Float16*)d_ws;            // 1 MB
    _Float16* wlo = whi + (size_t)NK * NH;      // 1 MB

    split_w<<<dim3(16, 4), 256, 0, stream>>>(W, whi, wlo);
    fused_main<<<dim3(NB, NH / HB), 512, 0, stream>>>(x, whi, wlo, bias, out);
}

// Round 7
// 196.346 us; speedup vs baseline: 1.1320x; 1.0349x over previous
//
#include <hip/hip_runtime.h>
#include <stdint.h>

// proj = einsum('bit,ih->tbh', x, W); scan: h=relu(p+0.8h(1-y)); y=thr(h+b,1).
// B=64, K=512, T=512, H=1024 fp32. Output: final y (64x1024).
//
// R12: decoupled in-kernel x split. R11 proved the residual win (96->68us:
// no x-prepass, 2MB ws) but regressed fused 95->135us because the scalar
// A-read + VALU split sat INSIDE the MFMA cluster with zero load-to-use
// distance (per-mi: 8 LDS latencies + serial convert feeding 12 MFMAs),
// duplicated per wn-wave. This round restores R7's exact consume path
// (fp16 fragment layout, ds_read_b128, 0 conflicts, 95us-proven) and
// produces the fp16 A-buffer in-kernel, pipelined one kt ahead:
//   per kt: issue 16 coalesced global_load_dword (next-kt fp32 A -> regs,
//   lane-contiguous t) + B DMA -> buf^1; run R7 MFMA cluster on buf;
//   then convert regs (bit-identical f=v*64; hh; hl=f-hh) and
//   ds_write_b128 into buf^1 in prepass fragment order (chunk swizzle
//   makes the write a full 32-bank sweep per 8 lanes -> conflict-free);
//   single wait_all_barrier per kt (R7 shape).
// Conversion cost: once per element per block (4x total, vs prepass 1x /
// R11 8x), with ~2000cyc of MFMA between load and use. W keeps its tiny
// prepass. Accumulation order unchanged -> absmax 0.03125.

#define NB 64
#define NK 512
#define NT 512
#define NH 1024

#define TB 256     // t per block tile
#define HB 256     // h per block tile
#define KK 32      // k per step
#define NKT (NK / KK)   // 16

typedef _Float16 h8_t __attribute__((ext_vector_type(8)));
typedef float    f4_t __attribute__((ext_vector_type(4)));

#define AS1 __attribute__((address_space(1)))
#define AS3 __attribute__((address_space(3)))

__device__ __forceinline__ void async_copy16(const void* g, void* l) {
    __builtin_amdgcn_global_load_lds((const AS1 uint32_t*)g, (AS3 uint32_t*)l, 16, 0, 0);
}

// full drain + barrier: one per k-iteration (R7 proven shape)
__device__ __forceinline__ void wait_all_barrier() {
    __builtin_amdgcn_s_waitcnt(0);   // vmcnt(0) expcnt(0) lgkmcnt(0)
    __syncthreads();
}

// ---- W-only pre-pass: fp32 [512][1024] -> fp16 hi/lo in fragment order
__global__ __launch_bounds__(256) void split_w(
    const float* __restrict__ Wm, _Float16* __restrict__ whi,
    _Float16* __restrict__ wlo)
{
    const int tid = threadIdx.x;
    const int cq  = tid & 15;     // col quad 0..15
    const int u   = tid >> 4;     // row octet 0..15

    const int bx = blockIdx.x;    // 0..15
    const int by = blockIdx.y;    // 0..3
    const int C  = NH;
    const int col0 = bx * 64;
    const int row0 = by * 128;
    const int ktbase = by * 4;

    const float* s = Wm + (size_t)(row0 + u * 8) * C + col0 + cq * 4;

    f4_t v[8];
    #pragma unroll
    for (int j = 0; j < 8; ++j)
        v[j] = *(const f4_t*)(s + (size_t)j * C);

    const int kt = ktbase + (u >> 2);
    const int ck = u & 3;

    #pragma unroll
    for (int i = 0; i < 4; ++i) {
        h8_t hi, lo;
        #pragma unroll
        for (int j = 0; j < 8; ++j) {
            float f = v[j][i] * 64.0f;       // 2^6 pre-scale
            _Float16 hh = (_Float16)f;
            hi[j] = hh;
            lo[j] = (_Float16)(f - (float)hh);
        }
        const int col = col0 + cq * 4 + i;
        const int ckp = ck ^ ((col >> 1) & 3);
        const size_t off = ((size_t)kt * C + col) * 32 + (size_t)ckp * 8;
        *(h8_t*)(whi + off) = hi;
        *(h8_t*)(wlo + off) = lo;
    }
}

// ---------------- main fused kernel (R12: decoupled in-kernel A split) --------
__global__ __launch_bounds__(512, 2) void fused_main(
    const float* __restrict__ X,
    const _Float16* __restrict__ whi, const _Float16* __restrict__ wlo,
    const float* __restrict__ bias, float* __restrict__ out)
{
    // [buf][arr][8192] halfs; arr: 0=Ahi 1=Alo 2=Bhi 3=Blo. 131072 B total.
    // A arrays hold the SAME fp16 fragment layout as the old prepass output.
    __shared__ __align__(16) _Float16 SMEM[2][4][TB * KK];
    // Epilogue P aliases buf1 (64 KB): P[64][256] fp32, XOR-bit4 swizzled.
    float* Pf = (float*)&SMEM[1][0][0];

    const int tid  = threadIdx.x;
    const int lane = tid & 63;
    const int wid  = tid >> 6;     // 0..7
    const int l15  = lane & 15;
    const int lq   = lane >> 4;    // 0..3
    const int wm   = wid >> 1;     // t quarter 0..3
    const int wn   = wid & 1;      // h half 0..1

    const int b  = blockIdx.x;
    const int h0 = blockIdx.y * HB;

    // fragment LDS offsets (halfs); chunk swizzle matches layout
    const int sw   = (l15 >> 1) & 3;
    const int aoff = ((wm * 64 + l15) * 4 + (lq ^ sw)) * 8;   // + mi*512
    const int boff = ((wn * 128 + l15) * 4 + (lq ^ sw)) * 8;  // + ni*512

    float hs = 0.0f, ys = 0.0f, bv = 0.0f;
    if (tid < HB) bv = bias[h0 + tid];

    const float INV_SCALE = 1.0f / 4096.0f;   // undo 2^6 x 2^6 operand scales

    // A staging, register-mediated. Thread owns t = tid&255 and chunk pair
    // ck = (tid>>8)*2 + {0,1}. Loads: per (ck,j) lane-contiguous in t
    // (256B/instr). Writes: h8 at (t*4+ckp)*8 halfs, ckp = ck^((t>>1)&3)
    // -> per 8 lanes the starting banks sweep all 8 quads: conflict-free.
    auto loadA = [&](int tt, int kt, float (&av)[2][8]) {
        const int tloc = tid & 255;
        #pragma unroll
        for (int cc = 0; cc < 2; ++cc) {
            const int k = kt * KK + ((tid >> 8) * 2 + cc) * 8;
            const float* g = X + ((size_t)(b * NK + k)) * NT + tt + tloc;
            #pragma unroll
            for (int j = 0; j < 8; ++j)
                av[cc][j] = g[(size_t)j * NT];
        }
    };
    auto writeA = [&](int buf, const float (&av)[2][8]) {
        const int tloc = tid & 255;
        #pragma unroll
        for (int cc = 0; cc < 2; ++cc) {
            const int ck  = (tid >> 8) * 2 + cc;
            const int ckp = ck ^ ((tloc >> 1) & 3);
            h8_t hi, lo;
            #pragma unroll
            for (int j = 0; j < 8; ++j) {
                float f = av[cc][j] * 64.0f;     // bit-identical split
                _Float16 hh = (_Float16)f;
                hi[j] = hh;
                lo[j] = (_Float16)(f - (float)hh);
            }
            const int off = (tloc * 4 + ckp) * 8;
            *(h8_t*)(&SMEM[buf][0][off]) = hi;
            *(h8_t*)(&SMEM[buf][1][off]) = lo;
        }
    };
    auto stage_B = [&](int kt, int buf) {
        const _Float16* gb_hi = whi + ((size_t)kt * NH + h0) * KK;
        const _Float16* gb_lo = wlo + ((size_t)kt * NH + h0) * KK;
        #pragma unroll
        for (int c = 0; c < 2; ++c) {
            const int ch = tid + c * 512;
            async_copy16(gb_hi + ch * 8, &SMEM[buf][2][ch * 8]);
            async_copy16(gb_lo + ch * 8, &SMEM[buf][3][ch * 8]);
        }
    };

    f4_t acc[4][8];

    // initial prologue: fill buf0 for (tt0=0, kt=0)
    {
        float av0[2][8];
        loadA(0, 0, av0);
        stage_B(0, 0);
        writeA(0, av0);   // compiler inserts vmcnt waits before converts
    }

    for (int tt0 = 0; tt0 < NT; tt0 += TB) {
        #pragma unroll
        for (int mi = 0; mi < 4; ++mi)
            #pragma unroll
            for (int ni = 0; ni < 8; ++ni) {
                f4_t z = {0.f, 0.f, 0.f, 0.f};
                acc[mi][ni] = z;
            }

        wait_all_barrier();   // prologue buf0 (A writes + B DMA) visible

        for (int kt = 0; kt < NKT; ++kt) {
            const int cur = kt & 1;

            // issue next-kt A loads (regs) + B DMA early; they fly under MFMA
            float av[2][8];
            if (kt + 1 < NKT) { loadA(tt0, kt + 1, av); stage_B(kt + 1, cur ^ 1); }

            h8_t bh[8], bl[8];
            #pragma unroll
            for (int ni = 0; ni < 8; ++ni) {
                bh[ni] = *(const h8_t*)(&SMEM[cur][2][boff + ni * 512]);
                bl[ni] = *(const h8_t*)(&SMEM[cur][3][boff + ni * 512]);
            }
            __builtin_amdgcn_s_setprio(1);
            #pragma unroll
            for (int mi = 0; mi < 4; ++mi) {
                h8_t ah = *(const h8_t*)(&SMEM[cur][0][aoff + mi * 512]);
                h8_t al = *(const h8_t*)(&SMEM[cur][1][aoff + mi * 512]);
                #pragma unroll
                for (int ni = 0; ni < 8; ++ni) {
                    acc[mi][ni] = __builtin_amdgcn_mfma_f32_16x16x32_f16(ah, bh[ni], acc[mi][ni], 0, 0, 0);
                    acc[mi][ni] = __builtin_amdgcn_mfma_f32_16x16x32_f16(ah, bl[ni], acc[mi][ni], 0, 0, 0);
                    acc[mi][ni] = __builtin_amdgcn_mfma_f32_16x16x32_f16(al, bh[ni], acc[mi][ni], 0, 0, 0);
                }
            }
            __builtin_amdgcn_s_setprio(0);

            // convert + write next-kt A into buf^1 (loads landed under MFMA)
            if (kt + 1 < NKT) writeA(cur ^ 1, av);

            wait_all_barrier();   // B DMA + A writes done; frag reads retired
        }

        // pre-issue next t-tile's first stage: loads + B DMA before epilogue
        // (latency hidden under epilogue); convert+write after it.
        float avn[2][8];
        if (tt0 + TB < NT) { loadA(tt0 + TB, 0, avn); stage_B(0, 0); }

        // epilogue: 4 t-subtiles x 64 rows; P[64][256] fp32 aliased on buf1.
        // Swizzle: col' = col ^ (((row>>2)&1)<<4); writer key (lq&1) == reader
        // key ((m>>2)&1) since row = mi*16 + lq*4 + r. 2-way banks both sides.
        #pragma unroll 1
        for (int sub = 0; sub < 4; ++sub) {
            if (wm == sub) {
                #pragma unroll
                for (int mi = 0; mi < 4; ++mi)
                    #pragma unroll
                    for (int ni = 0; ni < 8; ++ni)
                        #pragma unroll
                        for (int r = 0; r < 4; ++r) {
                            const int row = mi * 16 + lq * 4 + r;
                            const int col = (wn * 128 + ni * 16 + l15) ^ ((lq & 1) << 4);
                            Pf[row * 256 + col] = acc[mi][ni][r] * INV_SCALE;
                        }
            }
            __syncthreads();
            if (tid < HB) {
                const int cc2 = tid;   // h within block tile, 0..255
                #pragma unroll 8
                for (int m = 0; m < 64; ++m) {
                    float p = Pf[m * 256 + (cc2 ^ (((m >> 2) & 1) << 4))];
                    float pre = p + 0.8f * hs * (1.0f - ys);
                    hs = pre > 0.0f ? pre : 0.0f;
                    float z = hs + bv;
                    ys = (z > 1.0f) ? z : 0.0f;
                }
            }
            __syncthreads();   // scan done before next sub overwrites P
        }

        // convert + write next tile's buf0 A (P on buf1 untouched);
        // visibility via the t-loop-top wait_all_barrier.
        if (tt0 + TB < NT) writeA(0, avn);
    }

    if (tid < HB)
        out[(size_t)b * NH + h0 + tid] = ys;
}

extern "C" void kernel_launch(void* const* d_in, const int* in_sizes, int n_in,
                              void* d_out, int out_size, void* d_ws, size_t ws_size,
                              hipStream_t stream) {
    const float* x    = (const float*)d_in[0];  // [64][512][512]
    const float* W    = (const float*)d_in[1];  // [512][1024]
    const float* bias = (const float*)d_in[2];  // [1024]
    float* out = (float*)d_out;

    _Float16* whi = (_Float16*)d_ws;            // 1 MB
    _Float16* wlo = whi + (size_t)NK * NH;      // 1 MB

    split_w<<<dim3(16, 4), 256, 0, stream>>>(W, whi, wlo);
    fused_main<<<dim3(NB, NH / HB), 512, 0, stream>>>(x, whi, wlo, bias, out);
}

// Round 8
// 182.756 us; speedup vs baseline: 1.2162x; 1.0744x over previous
//
#include <hip/hip_runtime.h>
#include <stdint.h>

// proj = einsum('bit,ih->tbh', x, W); scan: h=relu(p+0.8h(1-y)); y=thr(h+b,1).
// B=64, K=512, T=512, H=1024 fp32. Output: final y (64x1024).
//
// R13: de-spill R12. R12's WRITE_SIZE=34.5MB (vs R7 0.26MB) = scratch
// spills: unified reg file at 2 waves/SIMD caps 256/lane; acc[4][8]=128
// (AGPR) leaves 128 VGPRs; R12's resident bh/bl[8] (64) + av (16, live
// across cluster) + avn (16, live across the WHOLE epilogue) blew the cap
// -> ~270B/thread scratch on the MFMA critical path (MfmaUtil 34, 126us).
// Fixes, both exact-preserving:
//  1) cluster loop inverted to ni-outer/mi-inner: resident frags become
//     ah/al[4] (32 VGPR) + one transient bh/bl pair (8) instead of
//     bh/bl[8] (64). Per-acc-element MFMA chain order unchanged (hh,hl,lh
//     per kt, kt ascending) -> bit-identical.
//  2) avn eliminated: next-t-tile A load+convert+write runs sequentially
//     AFTER the epilogue (exposes ~600cyc twice per kernel, frees 16 regs
//     across ~500 epilogue instrs).
// Budget: ah/al 32 + bh/bl 8 + av 16 + addr/temps ~35 = ~91 < 128 -> no
// spill. Everything else = R12 (in-kernel x split, reg-mediated A staging,
// fragment-order ds_write (conflict-free), W-only prepass, 2MB ws).
// absmax must hold at 0.03125.

#define NB 64
#define NK 512
#define NT 512
#define NH 1024

#define TB 256     // t per block tile
#define HB 256     // h per block tile
#define KK 32      // k per step
#define NKT (NK / KK)   // 16

typedef _Float16 h8_t __attribute__((ext_vector_type(8)));
typedef float    f4_t __attribute__((ext_vector_type(4)));

#define AS1 __attribute__((address_space(1)))
#define AS3 __attribute__((address_space(3)))

__device__ __forceinline__ void async_copy16(const void* g, void* l) {
    __builtin_amdgcn_global_load_lds((const AS1 uint32_t*)g, (AS3 uint32_t*)l, 16, 0, 0);
}

// full drain + barrier: one per k-iteration (R7 proven shape)
__device__ __forceinline__ void wait_all_barrier() {
    __builtin_amdgcn_s_waitcnt(0);   // vmcnt(0) expcnt(0) lgkmcnt(0)
    __syncthreads();
}

// ---- W-only pre-pass: fp32 [512][1024] -> fp16 hi/lo in fragment order
__global__ __launch_bounds__(256) void split_w(
    const float* __restrict__ Wm, _Float16* __restrict__ whi,
    _Float16* __restrict__ wlo)
{
    const int tid = threadIdx.x;
    const int cq  = tid & 15;     // col quad 0..15
    const int u   = tid >> 4;     // row octet 0..15

    const int bx = blockIdx.x;    // 0..15
    const int by = blockIdx.y;    // 0..3
    const int C  = NH;
    const int col0 = bx * 64;
    const int row0 = by * 128;
    const int ktbase = by * 4;

    const float* s = Wm + (size_t)(row0 + u * 8) * C + col0 + cq * 4;

    f4_t v[8];
    #pragma unroll
    for (int j = 0; j < 8; ++j)
        v[j] = *(const f4_t*)(s + (size_t)j * C);

    const int kt = ktbase + (u >> 2);
    const int ck = u & 3;

    #pragma unroll
    for (int i = 0; i < 4; ++i) {
        h8_t hi, lo;
        #pragma unroll
        for (int j = 0; j < 8; ++j) {
            float f = v[j][i] * 64.0f;       // 2^6 pre-scale
            _Float16 hh = (_Float16)f;
            hi[j] = hh;
            lo[j] = (_Float16)(f - (float)hh);
        }
        const int col = col0 + cq * 4 + i;
        const int ckp = ck ^ ((col >> 1) & 3);
        const size_t off = ((size_t)kt * C + col) * 32 + (size_t)ckp * 8;
        *(h8_t*)(whi + off) = hi;
        *(h8_t*)(wlo + off) = lo;
    }
}

// ---------------- main fused kernel (R13: de-spilled in-kernel A split) -------
__global__ __launch_bounds__(512, 2) void fused_main(
    const float* __restrict__ X,
    const _Float16* __restrict__ whi, const _Float16* __restrict__ wlo,
    const float* __restrict__ bias, float* __restrict__ out)
{
    // [buf][arr][8192] halfs; arr: 0=Ahi 1=Alo 2=Bhi 3=Blo. 131072 B total.
    __shared__ __align__(16) _Float16 SMEM[2][4][TB * KK];
    // Epilogue P aliases buf1 (64 KB): P[64][256] fp32, XOR-bit4 swizzled.
    float* Pf = (float*)&SMEM[1][0][0];

    const int tid  = threadIdx.x;
    const int lane = tid & 63;
    const int wid  = tid >> 6;     // 0..7
    const int l15  = lane & 15;
    const int lq   = lane >> 4;    // 0..3
    const int wm   = wid >> 1;     // t quarter 0..3
    const int wn   = wid & 1;      // h half 0..1

    const int b  = blockIdx.x;
    const int h0 = blockIdx.y * HB;

    // fragment LDS offsets (halfs); chunk swizzle matches layout
    const int sw   = (l15 >> 1) & 3;
    const int aoff = ((wm * 64 + l15) * 4 + (lq ^ sw)) * 8;   // + mi*512
    const int boff = ((wn * 128 + l15) * 4 + (lq ^ sw)) * 8;  // + ni*512

    float hs = 0.0f, ys = 0.0f, bv = 0.0f;
    if (tid < HB) bv = bias[h0 + tid];

    const float INV_SCALE = 1.0f / 4096.0f;   // undo 2^6 x 2^6 operand scales

    // A staging, register-mediated (R12 layout, conflict-free fragment write)
    auto loadA = [&](int tt, int kt, float (&av)[2][8]) {
        const int tloc = tid & 255;
        #pragma unroll
        for (int cc = 0; cc < 2; ++cc) {
            const int k = kt * KK + ((tid >> 8) * 2 + cc) * 8;
            const float* g = X + ((size_t)(b * NK + k)) * NT + tt + tloc;
            #pragma unroll
            for (int j = 0; j < 8; ++j)
                av[cc][j] = g[(size_t)j * NT];
        }
    };
    auto writeA = [&](int buf, const float (&av)[2][8]) {
        const int tloc = tid & 255;
        #pragma unroll
        for (int cc = 0; cc < 2; ++cc) {
            const int ck  = (tid >> 8) * 2 + cc;
            const int ckp = ck ^ ((tloc >> 1) & 3);
            h8_t hi, lo;
            #pragma unroll
            for (int j = 0; j < 8; ++j) {
                float f = av[cc][j] * 64.0f;     // bit-identical split
                _Float16 hh = (_Float16)f;
                hi[j] = hh;
                lo[j] = (_Float16)(f - (float)hh);
            }
            const int off = (tloc * 4 + ckp) * 8;
            *(h8_t*)(&SMEM[buf][0][off]) = hi;
            *(h8_t*)(&SMEM[buf][1][off]) = lo;
        }
    };
    auto stage_B = [&](int kt, int buf) {
        const _Float16* gb_hi = whi + ((size_t)kt * NH + h0) * KK;
        const _Float16* gb_lo = wlo + ((size_t)kt * NH + h0) * KK;
        #pragma unroll
        for (int c = 0; c < 2; ++c) {
            const int ch = tid + c * 512;
            async_copy16(gb_hi + ch * 8, &SMEM[buf][2][ch * 8]);
            async_copy16(gb_lo + ch * 8, &SMEM[buf][3][ch * 8]);
        }
    };

    f4_t acc[4][8];

    // initial prologue: fill buf0 for (tt0=0, kt=0)
    {
        float av0[2][8];
        loadA(0, 0, av0);
        stage_B(0, 0);
        writeA(0, av0);   // compiler inserts vmcnt waits before converts
    }

    for (int tt0 = 0; tt0 < NT; tt0 += TB) {
        #pragma unroll
        for (int mi = 0; mi < 4; ++mi)
            #pragma unroll
            for (int ni = 0; ni < 8; ++ni) {
                f4_t z = {0.f, 0.f, 0.f, 0.f};
                acc[mi][ni] = z;
            }

        wait_all_barrier();   // prologue buf0 (A writes + B DMA) visible

        for (int kt = 0; kt < NKT; ++kt) {
            const int cur = kt & 1;

            // issue next-kt A loads (regs) + B DMA early; they fly under MFMA
            float av[2][8];
            if (kt + 1 < NKT) { loadA(tt0, kt + 1, av); stage_B(kt + 1, cur ^ 1); }

            // ni-outer / mi-inner cluster: resident ah/al[4] (32 VGPR),
            // transient bh/bl (8). Per-acc MFMA chain order unchanged.
            h8_t ah[4], al[4];
            #pragma unroll
            for (int mi = 0; mi < 4; ++mi) {
                ah[mi] = *(const h8_t*)(&SMEM[cur][0][aoff + mi * 512]);
                al[mi] = *(const h8_t*)(&SMEM[cur][1][aoff + mi * 512]);
            }
            __builtin_amdgcn_s_setprio(1);
            #pragma unroll
            for (int ni = 0; ni < 8; ++ni) {
                h8_t bh = *(const h8_t*)(&SMEM[cur][2][boff + ni * 512]);
                h8_t bl = *(const h8_t*)(&SMEM[cur][3][boff + ni * 512]);
                #pragma unroll
                for (int mi = 0; mi < 4; ++mi) {
                    acc[mi][ni] = __builtin_amdgcn_mfma_f32_16x16x32_f16(ah[mi], bh, acc[mi][ni], 0, 0, 0);
                    acc[mi][ni] = __builtin_amdgcn_mfma_f32_16x16x32_f16(ah[mi], bl, acc[mi][ni], 0, 0, 0);
                    acc[mi][ni] = __builtin_amdgcn_mfma_f32_16x16x32_f16(al[mi], bh, acc[mi][ni], 0, 0, 0);
                }
            }
            __builtin_amdgcn_s_setprio(0);

            // convert + write next-kt A into buf^1 (loads landed under MFMA)
            if (kt + 1 < NKT) writeA(cur ^ 1, av);

            wait_all_barrier();   // B DMA + A writes done; frag reads retired
        }

        // epilogue: 4 t-subtiles x 64 rows; P[64][256] fp32 aliased on buf1.
        // Swizzle: col' = col ^ (((row>>2)&1)<<4); writer key (lq&1) == reader
        // key ((m>>2)&1) since row = mi*16 + lq*4 + r. 2-way banks both sides.
        #pragma unroll 1
        for (int sub = 0; sub < 4; ++sub) {
            if (wm == sub) {
                #pragma unroll
                for (int mi = 0; mi < 4; ++mi)
                    #pragma unroll
                    for (int ni = 0; ni < 8; ++ni)
                        #pragma unroll
                        for (int r = 0; r < 4; ++r) {
                            const int row = mi * 16 + lq * 4 + r;
                            const int col = (wn * 128 + ni * 16 + l15) ^ ((lq & 1) << 4);
                            Pf[row * 256 + col] = acc[mi][ni][r] * INV_SCALE;
                        }
            }
            __syncthreads();
            if (tid < HB) {
                const int cc2 = tid;   // h within block tile, 0..255
                #pragma unroll 8
                for (int m = 0; m < 64; ++m) {
                    float p = Pf[m * 256 + (cc2 ^ (((m >> 2) & 1) << 4))];
                    float pre = p + 0.8f * hs * (1.0f - ys);
                    hs = pre > 0.0f ? pre : 0.0f;
                    float z = hs + bv;
                    ys = (z > 1.0f) ? z : 0.0f;
                }
            }
            __syncthreads();   // scan done before next sub overwrites P
        }

        // next t-tile's first stage: sequential after epilogue (short-lived
        // regs, no spill; ~600cyc exposed twice per kernel). Visibility via
        // the t-loop-top wait_all_barrier.
        if (tt0 + TB < NT) {
            float avn[2][8];
            loadA(tt0 + TB, 0, avn);
            stage_B(0, 0);
            writeA(0, avn);
        }
    }

    if (tid < HB)
        out[(size_t)b * NH + h0 + tid] = ys;
}

extern "C" void kernel_launch(void* const* d_in, const int* in_sizes, int n_in,
                              void* d_out, int out_size, void* d_ws, size_t ws_size,
                              hipStream_t stream) {
    const float* x    = (const float*)d_in[0];  // [64][512][512]
    const float* W    = (const float*)d_in[1];  // [512][1024]
    const float* bias = (const float*)d_in[2];  // [1024]
    float* out = (float*)d_out;

    _Float16* whi = (_Float16*)d_ws;            // 1 MB
    _Float16* wlo = whi + (size_t)NK * NH;      // 1 MB

    split_w<<<dim3(16, 4), 256, 0, stream>>>(W, whi, wlo);
    fused_main<<<dim3(NB, NH / HB), 512, 0, stream>>>(x, whi, wlo, bias, out);
}

// Round 9
// 180.803 us; speedup vs baseline: 1.2293x; 1.0108x over previous
//
#include <hip/hip_runtime.h>
#include <stdint.h>

// proj = einsum('bit,ih->tbh', x, W); scan: h=relu(p+0.8h(1-y)); y=thr(h+b,1).
// B=64, K=512, T=512, H=1024 fp32. Output: final y (64x1024).
//
// R14: break MFMA dependency chains. R13 (182.8us total, best) issues
// acc[mi][ni]: hh->hl->lh back-to-back = 3 DEPENDENT MFMAs (same acc);
// at ~5cyc issue / ~16-20cyc latency each triple stalls ~2x its issue
// time and 2 waves/SIMD fill at most half — fits MfmaUtil 38-43%.
// Changes (both bit-exact):
//  1) mode-outer reorder within each ni: for mode{hh,hl,lh}: for mi:
//     consecutive instrs target different accs; same-acc reuse distance
//     = 4 instr ~ latency. Per-acc FP order (hh,hl,lh; kt asc) unchanged.
//  2) writeA (next-kt A convert+ds_write) moved INSIDE the cluster
//     between ni=5 and ni=6: its global loads (issued pre-cluster) have
//     ~2800cyc; removes the serial tail before the barrier.
// Everything else = R13: in-kernel x split (no x-prepass, 2MB ws),
// reg-mediated A staging, fragment-order conflict-free ds_write, ni-outer
// frag residency (ah/al[4]+transient bh/bl, no spill), W-only prepass,
// single wait_all_barrier per kt, P aliased on buf1.
// absmax must hold at 0.03125.

#define NB 64
#define NK 512
#define NT 512
#define NH 1024

#define TB 256     // t per block tile
#define HB 256     // h per block tile
#define KK 32      // k per step
#define NKT (NK / KK)   // 16

typedef _Float16 h8_t __attribute__((ext_vector_type(8)));
typedef float    f4_t __attribute__((ext_vector_type(4)));

#define AS1 __attribute__((address_space(1)))
#define AS3 __attribute__((address_space(3)))

__device__ __forceinline__ void async_copy16(const void* g, void* l) {
    __builtin_amdgcn_global_load_lds((const AS1 uint32_t*)g, (AS3 uint32_t*)l, 16, 0, 0);
}

// full drain + barrier: one per k-iteration (R7 proven shape)
__device__ __forceinline__ void wait_all_barrier() {
    __builtin_amdgcn_s_waitcnt(0);   // vmcnt(0) expcnt(0) lgkmcnt(0)
    __syncthreads();
}

// ---- W-only pre-pass: fp32 [512][1024] -> fp16 hi/lo in fragment order
__global__ __launch_bounds__(256) void split_w(
    const float* __restrict__ Wm, _Float16* __restrict__ whi,
    _Float16* __restrict__ wlo)
{
    const int tid = threadIdx.x;
    const int cq  = tid & 15;     // col quad 0..15
    const int u   = tid >> 4;     // row octet 0..15

    const int bx = blockIdx.x;    // 0..15
    const int by = blockIdx.y;    // 0..3
    const int C  = NH;
    const int col0 = bx * 64;
    const int row0 = by * 128;
    const int ktbase = by * 4;

    const float* s = Wm + (size_t)(row0 + u * 8) * C + col0 + cq * 4;

    f4_t v[8];
    #pragma unroll
    for (int j = 0; j < 8; ++j)
        v[j] = *(const f4_t*)(s + (size_t)j * C);

    const int kt = ktbase + (u >> 2);
    const int ck = u & 3;

    #pragma unroll
    for (int i = 0; i < 4; ++i) {
        h8_t hi, lo;
        #pragma unroll
        for (int j = 0; j < 8; ++j) {
            float f = v[j][i] * 64.0f;       // 2^6 pre-scale
            _Float16 hh = (_Float16)f;
            hi[j] = hh;
            lo[j] = (_Float16)(f - (float)hh);
        }
        const int col = col0 + cq * 4 + i;
        const int ckp = ck ^ ((col >> 1) & 3);
        const size_t off = ((size_t)kt * C + col) * 32 + (size_t)ckp * 8;
        *(h8_t*)(whi + off) = hi;
        *(h8_t*)(wlo + off) = lo;
    }
}

// ---------------- main fused kernel (R14: chain-broken MFMA order) ------------
__global__ __launch_bounds__(512, 2) void fused_main(
    const float* __restrict__ X,
    const _Float16* __restrict__ whi, const _Float16* __restrict__ wlo,
    const float* __restrict__ bias, float* __restrict__ out)
{
    // [buf][arr][8192] halfs; arr: 0=Ahi 1=Alo 2=Bhi 3=Blo. 131072 B total.
    __shared__ __align__(16) _Float16 SMEM[2][4][TB * KK];
    // Epilogue P aliases buf1 (64 KB): P[64][256] fp32, XOR-bit4 swizzled.
    float* Pf = (float*)&SMEM[1][0][0];

    const int tid  = threadIdx.x;
    const int lane = tid & 63;
    const int wid  = tid >> 6;     // 0..7
    const int l15  = lane & 15;
    const int lq   = lane >> 4;    // 0..3
    const int wm   = wid >> 1;     // t quarter 0..3
    const int wn   = wid & 1;      // h half 0..1

    const int b  = blockIdx.x;
    const int h0 = blockIdx.y * HB;

    // fragment LDS offsets (halfs); chunk swizzle matches layout
    const int sw   = (l15 >> 1) & 3;
    const int aoff = ((wm * 64 + l15) * 4 + (lq ^ sw)) * 8;   // + mi*512
    const int boff = ((wn * 128 + l15) * 4 + (lq ^ sw)) * 8;  // + ni*512

    float hs = 0.0f, ys = 0.0f, bv = 0.0f;
    if (tid < HB) bv = bias[h0 + tid];

    const float INV_SCALE = 1.0f / 4096.0f;   // undo 2^6 x 2^6 operand scales

    // A staging, register-mediated (conflict-free fragment write)
    auto loadA = [&](int tt, int kt, float (&av)[2][8]) {
        const int tloc = tid & 255;
        #pragma unroll
        for (int cc = 0; cc < 2; ++cc) {
            const int k = kt * KK + ((tid >> 8) * 2 + cc) * 8;
            const float* g = X + ((size_t)(b * NK + k)) * NT + tt + tloc;
            #pragma unroll
            for (int j = 0; j < 8; ++j)
                av[cc][j] = g[(size_t)j * NT];
        }
    };
    auto writeA = [&](int buf, const float (&av)[2][8]) {
        const int tloc = tid & 255;
        #pragma unroll
        for (int cc = 0; cc < 2; ++cc) {
            const int ck  = (tid >> 8) * 2 + cc;
            const int ckp = ck ^ ((tloc >> 1) & 3);
            h8_t hi, lo;
            #pragma unroll
            for (int j = 0; j < 8; ++j) {
                float f = av[cc][j] * 64.0f;     // bit-identical split
                _Float16 hh = (_Float16)f;
                hi[j] = hh;
                lo[j] = (_Float16)(f - (float)hh);
            }
            const int off = (tloc * 4 + ckp) * 8;
            *(h8_t*)(&SMEM[buf][0][off]) = hi;
            *(h8_t*)(&SMEM[buf][1][off]) = lo;
        }
    };
    auto stage_B = [&](int kt, int buf) {
        const _Float16* gb_hi = whi + ((size_t)kt * NH + h0) * KK;
        const _Float16* gb_lo = wlo + ((size_t)kt * NH + h0) * KK;
        #pragma unroll
        for (int c = 0; c < 2; ++c) {
            const int ch = tid + c * 512;
            async_copy16(gb_hi + ch * 8, &SMEM[buf][2][ch * 8]);
            async_copy16(gb_lo + ch * 8, &SMEM[buf][3][ch * 8]);
        }
    };

    // one ni-column of the cluster: 12 MFMAs, mode-outer / mi-inner.
    // Per-acc chain order stays hh -> hl -> lh (bit-exact); consecutive
    // instructions hit different accumulators (reuse distance 4).
    f4_t acc[4][8];
    auto mfma_col = [&](int cur, int ni, const h8_t (&ah)[4], const h8_t (&al)[4]) {
        h8_t bh = *(const h8_t*)(&SMEM[cur][2][boff + ni * 512]);
        h8_t bl = *(const h8_t*)(&SMEM[cur][3][boff + ni * 512]);
        #pragma unroll
        for (int mi = 0; mi < 4; ++mi)
            acc[mi][ni] = __builtin_amdgcn_mfma_f32_16x16x32_f16(ah[mi], bh, acc[mi][ni], 0, 0, 0);
        #pragma unroll
        for (int mi = 0; mi < 4; ++mi)
            acc[mi][ni] = __builtin_amdgcn_mfma_f32_16x16x32_f16(ah[mi], bl, acc[mi][ni], 0, 0, 0);
        #pragma unroll
        for (int mi = 0; mi < 4; ++mi)
            acc[mi][ni] = __builtin_amdgcn_mfma_f32_16x16x32_f16(al[mi], bh, acc[mi][ni], 0, 0, 0);
    };

    // initial prologue: fill buf0 for (tt0=0, kt=0)
    {
        float av0[2][8];
        loadA(0, 0, av0);
        stage_B(0, 0);
        writeA(0, av0);   // compiler inserts vmcnt waits before converts
    }

    for (int tt0 = 0; tt0 < NT; tt0 += TB) {
        #pragma unroll
        for (int mi = 0; mi < 4; ++mi)
            #pragma unroll
            for (int ni = 0; ni < 8; ++ni) {
                f4_t z = {0.f, 0.f, 0.f, 0.f};
                acc[mi][ni] = z;
            }

        wait_all_barrier();   // prologue buf0 (A writes + B DMA) visible

        for (int kt = 0; kt < NKT; ++kt) {
            const int cur = kt & 1;
            const bool more = (kt + 1 < NKT);

            // issue next-kt A loads (regs) + B DMA early; they fly under MFMA
            float av[2][8];
            if (more) { loadA(tt0, kt + 1, av); stage_B(kt + 1, cur ^ 1); }

            h8_t ah[4], al[4];
            #pragma unroll
            for (int mi = 0; mi < 4; ++mi) {
                ah[mi] = *(const h8_t*)(&SMEM[cur][0][aoff + mi * 512]);
                al[mi] = *(const h8_t*)(&SMEM[cur][1][aoff + mi * 512]);
            }
            __builtin_amdgcn_s_setprio(1);
            #pragma unroll
            for (int ni = 0; ni < 6; ++ni)
                mfma_col(cur, ni, ah, al);
            // convert + write next-kt A under the cluster tail (loads have
            // had ~2800cyc; dest buf^1 is not read until after the barrier)
            if (more) writeA(cur ^ 1, av);
            #pragma unroll
            for (int ni = 6; ni < 8; ++ni)
                mfma_col(cur, ni, ah, al);
            __builtin_amdgcn_s_setprio(0);

            wait_all_barrier();   // B DMA + A writes done; frag reads retired
        }

        // epilogue: 4 t-subtiles x 64 rows; P[64][256] fp32 aliased on buf1.
        // Swizzle: col' = col ^ (((row>>2)&1)<<4); writer key (lq&1) == reader
        // key ((m>>2)&1) since row = mi*16 + lq*4 + r. 2-way banks both sides.
        #pragma unroll 1
        for (int sub = 0; sub < 4; ++sub) {
            if (wm == sub) {
                #pragma unroll
                for (int mi = 0; mi < 4; ++mi)
                    #pragma unroll
                    for (int ni = 0; ni < 8; ++ni)
                        #pragma unroll
                        for (int r = 0; r < 4; ++r) {
                            const int row = mi * 16 + lq * 4 + r;
                            const int col = (wn * 128 + ni * 16 + l15) ^ ((lq & 1) << 4);
                            Pf[row * 256 + col] = acc[mi][ni][r] * INV_SCALE;
                        }
            }
            __syncthreads();
            if (tid < HB) {
                const int cc2 = tid;   // h within block tile, 0..255
                #pragma unroll 8
                for (int m = 0; m < 64; ++m) {
                    float p = Pf[m * 256 + (cc2 ^ (((m >> 2) & 1) << 4))];
                    float pre = p + 0.8f * hs * (1.0f - ys);
                    hs = pre > 0.0f ? pre : 0.0f;
                    float z = hs + bv;
                    ys = (z > 1.0f) ? z : 0.0f;
                }
            }
            __syncthreads();   // scan done before next sub overwrites P
        }

        // next t-tile's first stage: sequential after epilogue (short-lived
        // regs, no spill). Visibility via the t-loop-top wait_all_barrier.
        if (tt0 + TB < NT) {
            float avn[2][8];
            loadA(tt0 + TB, 0, avn);
            stage_B(0, 0);
            writeA(0, avn);
        }
    }

    if (tid < HB)
        out[(size_t)b * NH + h0 + tid] = ys;
}

extern "C" void kernel_launch(void* const* d_in, const int* in_sizes, int n_in,
                              void* d_out, int out_size, void* d_ws, size_t ws_size,
                              hipStream_t stream) {
    const float* x    = (const float*)d_in[0];  // [64][512][512]
    const float* W    = (const float*)d_in[1];  // [512][1024]
    const float* bias = (const float*)d_in[2];  // [1024]
    float* out = (float*)d_out;

    _Float16* whi = (_Float16*)d_ws;            // 1 MB
    _Float16* wlo = whi + (size_t)NK * NH;      // 1 MB

    split_w<<<dim3(16, 4), 256, 0, stream>>>(W, whi, wlo);
    fused_main<<<dim3(NB, NH / HB), 512, 0, stream>>>(x, whi, wlo, bias, out);
}